// Round 2
// baseline (217.444 us; speedup 1.0000x reference)
//
#include <hip/hip_runtime.h>
#include <math.h>

#define N 4096
#define P 128
#define H 4
#define E 32
#define NSEG 32

// ---------------------------------------------------------------------------
// Kernel A: counting sort of row indices by segment id. Single block.
// Ballot-based: one LDS atomic per wave per segment (not per element).
// ---------------------------------------------------------------------------
__global__ __launch_bounds__(256) void seg_sort_kernel(const int* __restrict__ pos,
                                                       int* __restrict__ seg_rows,
                                                       int* __restrict__ seg_off) {
    __shared__ int cnt[NSEG];
    __shared__ int off[NSEG + 1];
    __shared__ int cur[NSEG];
    const int t = threadIdx.x;
    const int lane = t & 63;
    const int wv = t >> 6;
    if (t < NSEG) cnt[t] = 0;
    __syncthreads();
    // phase 1: count via ballot (1 atomic per wave per present segment)
    for (int base = wv * 64; base < N; base += 256) {
        int v = pos[base + lane];
        for (int s = 0; s < NSEG; ++s) {
            unsigned long long mask = __ballot(v == s);
            if (mask && lane == (__ffsll((long long)mask) - 1))
                atomicAdd(&cnt[s], (int)__popcll(mask));
        }
    }
    __syncthreads();
    if (t == 0) {
        int s = 0;
        for (int k = 0; k < NSEG; ++k) { off[k] = s; s += cnt[k]; }
        off[NSEG] = s;
    }
    __syncthreads();
    if (t <= NSEG) seg_off[t] = off[t];
    if (t < NSEG) cur[t] = off[t];
    __syncthreads();
    // phase 2: scatter via ballot ranks
    for (int base = wv * 64; base < N; base += 256) {
        int i = base + lane;
        int v = pos[i];
        for (int s = 0; s < NSEG; ++s) {
            unsigned long long mask = __ballot(v == s);
            if (mask == 0ull) continue;                 // wave-uniform
            int leader = __ffsll((long long)mask) - 1;
            int b = 0;
            if (lane == leader) b = atomicAdd(&cur[s], (int)__popcll(mask));
            b = __shfl(b, leader);
            if (v == s) {
                int rank = (int)__popcll(mask & ((1ull << lane) - 1ull));
                seg_rows[b + rank] = i;
            }
        }
    }
}

// ---------------------------------------------------------------------------
// Kernel B: fused QKV projection, 32-row tiles for 2x the blocks (384).
// Grid: (N/32, 3). Block 256. LDS: 16KB X + 16KB W. 4x4-col micro-tile.
// ---------------------------------------------------------------------------
__global__ __launch_bounds__(256) void proj_kernel(const float* __restrict__ x,
                                                   const float* __restrict__ Wq,
                                                   const float* __restrict__ bq,
                                                   const float* __restrict__ Wk,
                                                   const float* __restrict__ bk,
                                                   const float* __restrict__ Wv,
                                                   const float* __restrict__ bv,
                                                   float* __restrict__ Q,
                                                   float* __restrict__ Ko,
                                                   float* __restrict__ Vo) {
    __shared__ float Xl[32][128];   // 16 KB
    __shared__ float Wl[32][128];   // 16 KB

    const int mat = blockIdx.y;
    const float* W = (mat == 0) ? Wq : (mat == 1) ? Wk : Wv;
    const float* b = (mat == 0) ? bq : (mat == 1) ? bk : bv;
    float* y       = (mat == 0) ? Q  : (mat == 1) ? Ko : Vo;

    const int t  = threadIdx.x;
    const int r0 = blockIdx.x * 32;

    for (int i = t * 4; i < 32 * 128; i += 256 * 4) {
        *(float4*)((float*)Xl + i) = *(const float4*)(x + r0 * 128 + i);
    }

    const int tc = t & 31;   // cols 4*tc..4*tc+3
    const int tr = t >> 5;   // rows 4*tr..4*tr+3

    float4 bb = *(const float4*)(b + tc * 4);
    float4 acc[4];
#pragma unroll
    for (int r = 0; r < 4; ++r) acc[r] = bb;

    for (int kc = 0; kc < 128; kc += 32) {
        __syncthreads();
        for (int i = t * 4; i < 32 * 128; i += 256 * 4) {
            *(float4*)((float*)Wl + i) = *(const float4*)(W + kc * 128 + i);
        }
        __syncthreads();
#pragma unroll
        for (int k0 = 0; k0 < 32; k0 += 4) {
            float4 w0 = *(float4*)&Wl[k0 + 0][tc * 4];
            float4 w1 = *(float4*)&Wl[k0 + 1][tc * 4];
            float4 w2 = *(float4*)&Wl[k0 + 2][tc * 4];
            float4 w3 = *(float4*)&Wl[k0 + 3][tc * 4];
#pragma unroll
            for (int r = 0; r < 4; ++r) {
                float4 xv = *(float4*)&Xl[tr * 4 + r][kc + k0];
                acc[r].x = fmaf(xv.x, w0.x, acc[r].x);
                acc[r].y = fmaf(xv.x, w0.y, acc[r].y);
                acc[r].z = fmaf(xv.x, w0.z, acc[r].z);
                acc[r].w = fmaf(xv.x, w0.w, acc[r].w);
                acc[r].x = fmaf(xv.y, w1.x, acc[r].x);
                acc[r].y = fmaf(xv.y, w1.y, acc[r].y);
                acc[r].z = fmaf(xv.y, w1.z, acc[r].z);
                acc[r].w = fmaf(xv.y, w1.w, acc[r].w);
                acc[r].x = fmaf(xv.z, w2.x, acc[r].x);
                acc[r].y = fmaf(xv.z, w2.y, acc[r].y);
                acc[r].z = fmaf(xv.z, w2.z, acc[r].z);
                acc[r].w = fmaf(xv.z, w2.w, acc[r].w);
                acc[r].x = fmaf(xv.w, w3.x, acc[r].x);
                acc[r].y = fmaf(xv.w, w3.y, acc[r].y);
                acc[r].z = fmaf(xv.w, w3.z, acc[r].z);
                acc[r].w = fmaf(xv.w, w3.w, acc[r].w);
            }
        }
    }

#pragma unroll
    for (int r = 0; r < 4; ++r) {
        *(float4*)(y + (size_t)(r0 + tr * 4 + r) * 128 + tc * 4) = acc[r];
    }
}

// ---------------------------------------------------------------------------
// Kernel C: split-K attention. Grid (NSEG, H, S). Each block computes
// online-softmax partials (m, l, acc[E]) over its key-slice for every query
// of the segment; merge_kernel combines the S partials per (row, head).
// ---------------------------------------------------------------------------
#define CH 96

template <int S>
__global__ __launch_bounds__(256) void attn_kernel(const float* __restrict__ Q,
                                                   const float* __restrict__ K,
                                                   const float* __restrict__ V,
                                                   const int* __restrict__ seg_rows,
                                                   const int* __restrict__ seg_off,
                                                   float2* __restrict__ partML,
                                                   float* __restrict__ partAcc) {
    __shared__ float Ks[CH][E];   // 12 KB
    __shared__ float Vs[CH][E];   // 12 KB

    const int s   = blockIdx.x;
    const int h   = blockIdx.y;
    const int sp  = blockIdx.z;
    const int beg = seg_off[s];
    const int len = seg_off[s + 1] - beg;
    const int t   = threadIdx.x;
    const float scale = 0.17677669529663687f;   // 1/sqrt(32)

    const int k0 = (int)(((long)len * sp) / S);
    const int k1 = (int)(((long)len * (sp + 1)) / S);
    const int sl = k1 - k0;

    for (int qb = 0; qb < len; qb += 256) {
        const int  qi     = qb + t;
        const bool active = (qi < len);
        const int  qrow   = active ? seg_rows[beg + qi] : 0;

        float q[E];
        if (active) {
#pragma unroll
            for (int e = 0; e < E; e += 4) {
                float4 v4 = *(const float4*)(Q + (size_t)qrow * P + h * E + e);
                q[e] = v4.x; q[e + 1] = v4.y; q[e + 2] = v4.z; q[e + 3] = v4.w;
            }
        }

        float m = -3.0e38f, l = 0.f;
        float acc[E];
#pragma unroll
        for (int e = 0; e < E; ++e) acc[e] = 0.f;

        for (int cb = 0; cb < sl; cb += CH) {
            const int cl = min(CH, sl - cb);
            __syncthreads();
            for (int idx = t; idx < cl * E; idx += 256) {
                int r = idx >> 5, e = idx & 31;
                int krow = seg_rows[beg + k0 + cb + r];
                Ks[r][e] = K[(size_t)krow * P + h * E + e];
                Vs[r][e] = V[(size_t)krow * P + h * E + e];
            }
            __syncthreads();
            if (active) {
                for (int r = 0; r < cl; ++r) {
                    // 4-way partial dot to break the serial FMA chain
                    float4 ka = *(float4*)&Ks[r][0];
                    float4 kb = *(float4*)&Ks[r][4];
                    float4 kc = *(float4*)&Ks[r][8];
                    float4 kd = *(float4*)&Ks[r][12];
                    float d0 = q[0] * ka.x + q[4] * kb.x;
                    float d1 = q[1] * ka.y + q[5] * kb.y;
                    float d2 = q[2] * ka.z + q[6] * kb.z;
                    float d3 = q[3] * ka.w + q[7] * kb.w;
                    d0 = fmaf(q[8],  kc.x, d0); d1 = fmaf(q[9],  kc.y, d1);
                    d2 = fmaf(q[10], kc.z, d2); d3 = fmaf(q[11], kc.w, d3);
                    d0 = fmaf(q[12], kd.x, d0); d1 = fmaf(q[13], kd.y, d1);
                    d2 = fmaf(q[14], kd.z, d2); d3 = fmaf(q[15], kd.w, d3);
                    float4 ke = *(float4*)&Ks[r][16];
                    float4 kf = *(float4*)&Ks[r][20];
                    float4 kg = *(float4*)&Ks[r][24];
                    float4 kh = *(float4*)&Ks[r][28];
                    d0 = fmaf(q[16], ke.x, d0); d1 = fmaf(q[17], ke.y, d1);
                    d2 = fmaf(q[18], ke.z, d2); d3 = fmaf(q[19], ke.w, d3);
                    d0 = fmaf(q[20], kf.x, d0); d1 = fmaf(q[21], kf.y, d1);
                    d2 = fmaf(q[22], kf.z, d2); d3 = fmaf(q[23], kf.w, d3);
                    d0 = fmaf(q[24], kg.x, d0); d1 = fmaf(q[25], kg.y, d1);
                    d2 = fmaf(q[26], kg.z, d2); d3 = fmaf(q[27], kg.w, d3);
                    d0 = fmaf(q[28], kh.x, d0); d1 = fmaf(q[29], kh.y, d1);
                    d2 = fmaf(q[30], kh.z, d2); d3 = fmaf(q[31], kh.w, d3);
                    float sc = ((d0 + d1) + (d2 + d3)) * scale;

                    float mn   = fmaxf(m, sc);
                    float corr = __expf(m - mn);
                    float p    = __expf(sc - mn);
                    l = l * corr + p;
#pragma unroll
                    for (int e = 0; e < E; ++e)
                        acc[e] = fmaf(p, Vs[r][e], acc[e] * corr);
                    m = mn;
                }
            }
        }

        if (active) {
            const size_t pidx = ((size_t)(beg + qi) * H + h) * S + sp;
            partML[pidx] = make_float2(m, l);
            float* pa = partAcc + pidx * E;
#pragma unroll
            for (int e = 0; e < E; e += 4) {
                float4 o;
                o.x = acc[e]; o.y = acc[e + 1]; o.z = acc[e + 2]; o.w = acc[e + 3];
                *(float4*)(pa + e) = o;
            }
        }
    }
}

// ---------------------------------------------------------------------------
// Kernel D: merge S partials per (sorted row, head), write final output.
// ---------------------------------------------------------------------------
template <int S>
__global__ __launch_bounds__(256) void merge_kernel(const float2* __restrict__ partML,
                                                    const float* __restrict__ partAcc,
                                                    const int* __restrict__ seg_rows,
                                                    float* __restrict__ out) {
    const int tid  = blockIdx.x * 256 + threadIdx.x;   // [0, N*H)
    const int sIdx = tid >> 2;
    const int h    = tid & 3;

    float2 ml[S];
    float  m = -3.0e38f;
#pragma unroll
    for (int sp = 0; sp < S; ++sp) {
        ml[sp] = partML[((size_t)sIdx * H + h) * S + sp];
        m = fmaxf(m, ml[sp].x);
    }
    float w[S];
    float l = 0.f;
#pragma unroll
    for (int sp = 0; sp < S; ++sp) {
        w[sp] = __expf(ml[sp].x - m);
        l = fmaf(ml[sp].y, w[sp], l);
    }
    const float inv = 1.0f / l;
    const int row = seg_rows[sIdx];

#pragma unroll
    for (int e = 0; e < E; e += 4) {
        float4 o = make_float4(0.f, 0.f, 0.f, 0.f);
#pragma unroll
        for (int sp = 0; sp < S; ++sp) {
            const float4 a = *(const float4*)(partAcc +
                               (((size_t)sIdx * H + h) * S + sp) * E + e);
            o.x = fmaf(a.x, w[sp], o.x);
            o.y = fmaf(a.y, w[sp], o.y);
            o.z = fmaf(a.z, w[sp], o.z);
            o.w = fmaf(a.w, w[sp], o.w);
        }
        o.x *= inv; o.y *= inv; o.z *= inv; o.w *= inv;
        *(float4*)(out + (size_t)row * P + h * E + e) = o;
    }
}

// ---------------------------------------------------------------------------
extern "C" void kernel_launch(void* const* d_in, const int* in_sizes, int n_in,
                              void* d_out, int out_size, void* d_ws, size_t ws_size,
                              hipStream_t stream) {
    const float* inp = (const float*)d_in[0];
    const int*   pos = (const int*)d_in[1];
    const float* Wq  = (const float*)d_in[2];
    const float* bq  = (const float*)d_in[3];
    const float* Wk  = (const float*)d_in[4];
    const float* bk  = (const float*)d_in[5];
    const float* Wv  = (const float*)d_in[6];
    const float* bv  = (const float*)d_in[7];
    float* out = (float*)d_out;

    // workspace layout
    float* Q  = (float*)d_ws;
    float* Kb = Q + (size_t)N * P;
    float* Vb = Kb + (size_t)N * P;
    int* seg_rows = (int*)(Vb + (size_t)N * P);
    int* seg_off  = seg_rows + N;
    char* after = (char*)(seg_off + NSEG + 1);
    size_t used = (size_t)(after - (char*)d_ws);
    used = (used + 15) & ~(size_t)15;
    float2* partML4 = (float2*)((char*)d_ws + used);

    auto need = [&](int S) {
        return used + (size_t)N * H * S * sizeof(float2)
                    + (size_t)N * H * S * E * sizeof(float);
    };

    seg_sort_kernel<<<1, 256, 0, stream>>>(pos, seg_rows, seg_off);
    proj_kernel<<<dim3(N / 32, 3), 256, 0, stream>>>(inp, Wq, bq, Wk, bk, Wv, bv, Q, Kb, Vb);

    if (ws_size >= need(4)) {
        constexpr int S = 4;
        float2* pml = partML4;
        float* pacc = (float*)(pml + (size_t)N * H * S);
        attn_kernel<S><<<dim3(NSEG, H, S), 256, 0, stream>>>(Q, Kb, Vb, seg_rows, seg_off, pml, pacc);
        merge_kernel<S><<<N * H / 256, 256, 0, stream>>>(pml, pacc, seg_rows, out);
    } else if (ws_size >= need(2)) {
        constexpr int S = 2;
        float2* pml = partML4;
        float* pacc = (float*)(pml + (size_t)N * H * S);
        attn_kernel<S><<<dim3(NSEG, H, S), 256, 0, stream>>>(Q, Kb, Vb, seg_rows, seg_off, pml, pacc);
        merge_kernel<S><<<N * H / 256, 256, 0, stream>>>(pml, pacc, seg_rows, out);
    } else {
        constexpr int S = 1;
        float2* pml = partML4;
        float* pacc = (float*)(pml + (size_t)N * H * S);
        attn_kernel<S><<<dim3(NSEG, H, S), 256, 0, stream>>>(Q, Kb, Vb, seg_rows, seg_off, pml, pacc);
        merge_kernel<S><<<N * H / 256, 256, 0, stream>>>(pml, pacc, seg_rows, out);
    }
}

// Round 3
// 140.494 us; speedup vs baseline: 1.5477x; 1.5477x over previous
//
#include <hip/hip_runtime.h>
#include <math.h>

#define N 4096
#define P 128
#define H 4
#define E 32
#define NSEG 32

// ---------------------------------------------------------------------------
// Sort phase 1: per-block LDS histogram -> global atomic accumulate.
// ---------------------------------------------------------------------------
__global__ __launch_bounds__(256) void hist_kernel(const int* __restrict__ pos,
                                                   int* __restrict__ gcnt) {
    __shared__ int lc[NSEG];
    const int t = threadIdx.x;
    if (t < NSEG) lc[t] = 0;
    __syncthreads();
    const int i = blockIdx.x * 256 + t;
    atomicAdd(&lc[pos[i]], 1);
    __syncthreads();
    if (t < NSEG && lc[t]) atomicAdd(&gcnt[t], lc[t]);
}

// ---------------------------------------------------------------------------
// Sort phase 2: exclusive scan of 32 counts (trivial serial).
// ---------------------------------------------------------------------------
__global__ __launch_bounds__(64) void scan_kernel(const int* __restrict__ gcnt,
                                                  int* __restrict__ seg_off,
                                                  int* __restrict__ cur) {
    if (threadIdx.x == 0) {
        int s = 0;
        for (int k = 0; k < NSEG; ++k) { seg_off[k] = s; cur[k] = s; s += gcnt[k]; }
        seg_off[NSEG] = s;
    }
}

// ---------------------------------------------------------------------------
// Sort phase 3: per-block local ranks (LDS atomics), block reserves a range
// per segment with ONE global atomic, then scatters.
// ---------------------------------------------------------------------------
__global__ __launch_bounds__(256) void scatter_kernel(const int* __restrict__ pos,
                                                      int* __restrict__ cur,
                                                      int* __restrict__ seg_rows) {
    __shared__ int lc[NSEG];
    __shared__ int lbase[NSEG];
    const int t = threadIdx.x;
    if (t < NSEG) lc[t] = 0;
    __syncthreads();
    const int i = blockIdx.x * 256 + t;
    const int s = pos[i];
    const int r = atomicAdd(&lc[s], 1);      // local rank within block
    __syncthreads();
    if (t < NSEG && lc[t]) lbase[t] = atomicAdd(&cur[t], lc[t]);
    __syncthreads();
    seg_rows[lbase[s] + r] = i;
}

// ---------------------------------------------------------------------------
// Kernel B: fused QKV projection, 32-row tiles (384 blocks).
// ---------------------------------------------------------------------------
__global__ __launch_bounds__(256) void proj_kernel(const float* __restrict__ x,
                                                   const float* __restrict__ Wq,
                                                   const float* __restrict__ bq,
                                                   const float* __restrict__ Wk,
                                                   const float* __restrict__ bk,
                                                   const float* __restrict__ Wv,
                                                   const float* __restrict__ bv,
                                                   float* __restrict__ Q,
                                                   float* __restrict__ Ko,
                                                   float* __restrict__ Vo) {
    __shared__ float Xl[32][128];   // 16 KB
    __shared__ float Wl[32][128];   // 16 KB

    const int mat = blockIdx.y;
    const float* W = (mat == 0) ? Wq : (mat == 1) ? Wk : Wv;
    const float* b = (mat == 0) ? bq : (mat == 1) ? bk : bv;
    float* y       = (mat == 0) ? Q  : (mat == 1) ? Ko : Vo;

    const int t  = threadIdx.x;
    const int r0 = blockIdx.x * 32;

    for (int i = t * 4; i < 32 * 128; i += 256 * 4) {
        *(float4*)((float*)Xl + i) = *(const float4*)(x + r0 * 128 + i);
    }

    const int tc = t & 31;   // cols 4*tc..4*tc+3
    const int tr = t >> 5;   // rows 4*tr..4*tr+3

    float4 bb = *(const float4*)(b + tc * 4);
    float4 acc[4];
#pragma unroll
    for (int r = 0; r < 4; ++r) acc[r] = bb;

    for (int kc = 0; kc < 128; kc += 32) {
        __syncthreads();
        for (int i = t * 4; i < 32 * 128; i += 256 * 4) {
            *(float4*)((float*)Wl + i) = *(const float4*)(W + kc * 128 + i);
        }
        __syncthreads();
#pragma unroll
        for (int k0 = 0; k0 < 32; k0 += 4) {
            float4 w0 = *(float4*)&Wl[k0 + 0][tc * 4];
            float4 w1 = *(float4*)&Wl[k0 + 1][tc * 4];
            float4 w2 = *(float4*)&Wl[k0 + 2][tc * 4];
            float4 w3 = *(float4*)&Wl[k0 + 3][tc * 4];
#pragma unroll
            for (int r = 0; r < 4; ++r) {
                float4 xv = *(float4*)&Xl[tr * 4 + r][kc + k0];
                acc[r].x = fmaf(xv.x, w0.x, acc[r].x);
                acc[r].y = fmaf(xv.x, w0.y, acc[r].y);
                acc[r].z = fmaf(xv.x, w0.z, acc[r].z);
                acc[r].w = fmaf(xv.x, w0.w, acc[r].w);
                acc[r].x = fmaf(xv.y, w1.x, acc[r].x);
                acc[r].y = fmaf(xv.y, w1.y, acc[r].y);
                acc[r].z = fmaf(xv.y, w1.z, acc[r].z);
                acc[r].w = fmaf(xv.y, w1.w, acc[r].w);
                acc[r].x = fmaf(xv.z, w2.x, acc[r].x);
                acc[r].y = fmaf(xv.z, w2.y, acc[r].y);
                acc[r].z = fmaf(xv.z, w2.z, acc[r].z);
                acc[r].w = fmaf(xv.z, w2.w, acc[r].w);
                acc[r].x = fmaf(xv.w, w3.x, acc[r].x);
                acc[r].y = fmaf(xv.w, w3.y, acc[r].y);
                acc[r].z = fmaf(xv.w, w3.z, acc[r].z);
                acc[r].w = fmaf(xv.w, w3.w, acc[r].w);
            }
        }
    }

#pragma unroll
    for (int r = 0; r < 4; ++r) {
        *(float4*)(y + (size_t)(r0 + tr * 4 + r) * 128 + tc * 4) = acc[r];
    }
}

// ---------------------------------------------------------------------------
// Kernel C: split-K attention. Grid (NSEG, H, S), block 128 (segments avg
// 128 rows -> one query per thread). Online-softmax partials per key-slice.
// ---------------------------------------------------------------------------
#define CH 96
#define ABLK 128

template <int S>
__global__ __launch_bounds__(ABLK) void attn_kernel(const float* __restrict__ Q,
                                                    const float* __restrict__ K,
                                                    const float* __restrict__ V,
                                                    const int* __restrict__ seg_rows,
                                                    const int* __restrict__ seg_off,
                                                    float2* __restrict__ partML,
                                                    float* __restrict__ partAcc) {
    __shared__ float Ks[CH][E];   // 12 KB
    __shared__ float Vs[CH][E];   // 12 KB

    const int s   = blockIdx.x;
    const int h   = blockIdx.y;
    const int sp  = blockIdx.z;
    const int beg = seg_off[s];
    const int len = seg_off[s + 1] - beg;
    const int t   = threadIdx.x;
    const float scale = 0.17677669529663687f;   // 1/sqrt(32)

    const int k0 = (int)(((long)len * sp) / S);
    const int k1 = (int)(((long)len * (sp + 1)) / S);
    const int sl = k1 - k0;

    for (int qb = 0; qb < len; qb += ABLK) {
        const int  qi     = qb + t;
        const bool active = (qi < len);
        const int  qrow   = active ? seg_rows[beg + qi] : 0;

        float q[E];
        if (active) {
#pragma unroll
            for (int e = 0; e < E; e += 4) {
                float4 v4 = *(const float4*)(Q + (size_t)qrow * P + h * E + e);
                q[e] = v4.x; q[e + 1] = v4.y; q[e + 2] = v4.z; q[e + 3] = v4.w;
            }
        }

        float m = -3.0e38f, l = 0.f;
        float acc[E];
#pragma unroll
        for (int e = 0; e < E; ++e) acc[e] = 0.f;

        for (int cb = 0; cb < sl; cb += CH) {
            const int cl = min(CH, sl - cb);
            __syncthreads();
            for (int idx = t; idx < cl * E; idx += ABLK) {
                int r = idx >> 5, e = idx & 31;
                int krow = seg_rows[beg + k0 + cb + r];
                Ks[r][e] = K[(size_t)krow * P + h * E + e];
                Vs[r][e] = V[(size_t)krow * P + h * E + e];
            }
            __syncthreads();
            if (active) {
                for (int r = 0; r < cl; ++r) {
                    float4 ka = *(float4*)&Ks[r][0];
                    float4 kb = *(float4*)&Ks[r][4];
                    float4 kc = *(float4*)&Ks[r][8];
                    float4 kd = *(float4*)&Ks[r][12];
                    float d0 = q[0] * ka.x + q[4] * kb.x;
                    float d1 = q[1] * ka.y + q[5] * kb.y;
                    float d2 = q[2] * ka.z + q[6] * kb.z;
                    float d3 = q[3] * ka.w + q[7] * kb.w;
                    d0 = fmaf(q[8],  kc.x, d0); d1 = fmaf(q[9],  kc.y, d1);
                    d2 = fmaf(q[10], kc.z, d2); d3 = fmaf(q[11], kc.w, d3);
                    d0 = fmaf(q[12], kd.x, d0); d1 = fmaf(q[13], kd.y, d1);
                    d2 = fmaf(q[14], kd.z, d2); d3 = fmaf(q[15], kd.w, d3);
                    float4 ke = *(float4*)&Ks[r][16];
                    float4 kf = *(float4*)&Ks[r][20];
                    float4 kg = *(float4*)&Ks[r][24];
                    float4 kh = *(float4*)&Ks[r][28];
                    d0 = fmaf(q[16], ke.x, d0); d1 = fmaf(q[17], ke.y, d1);
                    d2 = fmaf(q[18], ke.z, d2); d3 = fmaf(q[19], ke.w, d3);
                    d0 = fmaf(q[20], kf.x, d0); d1 = fmaf(q[21], kf.y, d1);
                    d2 = fmaf(q[22], kf.z, d2); d3 = fmaf(q[23], kf.w, d3);
                    d0 = fmaf(q[24], kg.x, d0); d1 = fmaf(q[25], kg.y, d1);
                    d2 = fmaf(q[26], kg.z, d2); d3 = fmaf(q[27], kg.w, d3);
                    d0 = fmaf(q[28], kh.x, d0); d1 = fmaf(q[29], kh.y, d1);
                    d2 = fmaf(q[30], kh.z, d2); d3 = fmaf(q[31], kh.w, d3);
                    float sc = ((d0 + d1) + (d2 + d3)) * scale;

                    float mn   = fmaxf(m, sc);
                    float corr = __expf(m - mn);
                    float p    = __expf(sc - mn);
                    l = l * corr + p;
#pragma unroll
                    for (int e = 0; e < E; ++e)
                        acc[e] = fmaf(p, Vs[r][e], acc[e] * corr);
                    m = mn;
                }
            }
        }

        if (active) {
            const size_t pidx = ((size_t)(beg + qi) * H + h) * S + sp;
            partML[pidx] = make_float2(m, l);
            float* pa = partAcc + pidx * E;
#pragma unroll
            for (int e = 0; e < E; e += 4) {
                float4 o;
                o.x = acc[e]; o.y = acc[e + 1]; o.z = acc[e + 2]; o.w = acc[e + 3];
                *(float4*)(pa + e) = o;
            }
        }
    }
}

// ---------------------------------------------------------------------------
// Kernel D: merge S partials per (sorted row, head).
// ---------------------------------------------------------------------------
template <int S>
__global__ __launch_bounds__(256) void merge_kernel(const float2* __restrict__ partML,
                                                    const float* __restrict__ partAcc,
                                                    const int* __restrict__ seg_rows,
                                                    float* __restrict__ out) {
    const int tid  = blockIdx.x * 256 + threadIdx.x;   // [0, N*H)
    const int sIdx = tid >> 2;
    const int h    = tid & 3;

    float2 ml[S];
    float  m = -3.0e38f;
#pragma unroll
    for (int sp = 0; sp < S; ++sp) {
        ml[sp] = partML[((size_t)sIdx * H + h) * S + sp];
        m = fmaxf(m, ml[sp].x);
    }
    float w[S];
    float l = 0.f;
#pragma unroll
    for (int sp = 0; sp < S; ++sp) {
        w[sp] = __expf(ml[sp].x - m);
        l = fmaf(ml[sp].y, w[sp], l);
    }
    const float inv = 1.0f / l;
    const int row = seg_rows[sIdx];

#pragma unroll
    for (int e = 0; e < E; e += 4) {
        float4 o = make_float4(0.f, 0.f, 0.f, 0.f);
#pragma unroll
        for (int sp = 0; sp < S; ++sp) {
            const float4 a = *(const float4*)(partAcc +
                               (((size_t)sIdx * H + h) * S + sp) * E + e);
            o.x = fmaf(a.x, w[sp], o.x);
            o.y = fmaf(a.y, w[sp], o.y);
            o.z = fmaf(a.z, w[sp], o.z);
            o.w = fmaf(a.w, w[sp], o.w);
        }
        o.x *= inv; o.y *= inv; o.z *= inv; o.w *= inv;
        *(float4*)(out + (size_t)row * P + h * E + e) = o;
    }
}

// ---------------------------------------------------------------------------
template <int S>
static void run_attn(const float* Q, const float* Kb, const float* Vb,
                     const int* seg_rows, const int* seg_off,
                     float2* pml, float* pacc, float* out, hipStream_t stream) {
    attn_kernel<S><<<dim3(NSEG, H, S), ABLK, 0, stream>>>(Q, Kb, Vb, seg_rows, seg_off, pml, pacc);
    merge_kernel<S><<<N * H / 256, 256, 0, stream>>>(pml, pacc, seg_rows, out);
}

extern "C" void kernel_launch(void* const* d_in, const int* in_sizes, int n_in,
                              void* d_out, int out_size, void* d_ws, size_t ws_size,
                              hipStream_t stream) {
    const float* inp = (const float*)d_in[0];
    const int*   pos = (const int*)d_in[1];
    const float* Wq  = (const float*)d_in[2];
    const float* bq  = (const float*)d_in[3];
    const float* Wk  = (const float*)d_in[4];
    const float* bk  = (const float*)d_in[5];
    const float* Wv  = (const float*)d_in[6];
    const float* bv  = (const float*)d_in[7];
    float* out = (float*)d_out;

    // workspace layout
    float* Q  = (float*)d_ws;
    float* Kb = Q + (size_t)N * P;
    float* Vb = Kb + (size_t)N * P;
    int* seg_rows = (int*)(Vb + (size_t)N * P);
    int* seg_off  = seg_rows + N;          // NSEG+1
    int* gcnt     = seg_off + NSEG + 1;    // NSEG
    int* cur      = gcnt + NSEG;           // NSEG
    char* after = (char*)(cur + NSEG);
    size_t used = (size_t)(after - (char*)d_ws);
    used = (used + 15) & ~(size_t)15;
    float2* pmlBase = (float2*)((char*)d_ws + used);

    auto need = [&](int S) {
        return used + (size_t)N * H * S * sizeof(float2)
                    + (size_t)N * H * S * E * sizeof(float);
    };

    hipMemsetAsync(gcnt, 0, 2 * NSEG * sizeof(int), stream);
    hist_kernel<<<N / 256, 256, 0, stream>>>(pos, gcnt);
    scan_kernel<<<1, 64, 0, stream>>>(gcnt, seg_off, cur);
    scatter_kernel<<<N / 256, 256, 0, stream>>>(pos, cur, seg_rows);

    proj_kernel<<<dim3(N / 32, 3), 256, 0, stream>>>(inp, Wq, bq, Wk, bk, Wv, bv, Q, Kb, Vb);

    if (ws_size >= need(8)) {
        float2* pml = pmlBase;
        float* pacc = (float*)(pml + (size_t)N * H * 8);
        run_attn<8>(Q, Kb, Vb, seg_rows, seg_off, pml, pacc, out, stream);
    } else if (ws_size >= need(4)) {
        float2* pml = pmlBase;
        float* pacc = (float*)(pml + (size_t)N * H * 4);
        run_attn<4>(Q, Kb, Vb, seg_rows, seg_off, pml, pacc, out, stream);
    } else if (ws_size >= need(2)) {
        float2* pml = pmlBase;
        float* pacc = (float*)(pml + (size_t)N * H * 2);
        run_attn<2>(Q, Kb, Vb, seg_rows, seg_off, pml, pacc, out, stream);
    } else {
        float2* pml = pmlBase;
        float* pacc = (float*)(pml + (size_t)N * H * 1);
        run_attn<1>(Q, Kb, Vb, seg_rows, seg_off, pml, pacc, out, stream);
    }
}